// Round 1
// baseline (558.631 us; speedup 1.0000x reference)
//
#include <hip/hip_runtime.h>

// Problem constants
#define E_ 512
#define B_ 16
#define DIN_ 1024
#define H_ 8
#define T_ 3
#define D_ 128
#define NCOLS 1152            // 1024 (h*D h_last cols) + 48 (left/right cols) + pad to 9*128
#define NEGV (-1e30f)

// Workspace layout (in floats)
// Bp : [1024][1152]   packed B matrix (W_last columns + wa columns + zero pad)
// Y  : [8192][1152]   X @ Bp   (cols <1024 masked by node_mask)
// LRt: [48][8192]     transposed left/right columns for coalesced staging
#define Y_OFF  (1024 * NCOLS)                 // 1,179,648
#define LR_OFF (Y_OFF + 8192 * NCOLS)         // 10,616,832
// total ws floats = LR_OFF + 48*8192 = 11,010,048  -> 44,040,192 bytes

// ---------------------------------------------------------------------------
// Kernel 1: pack Bp[k][n]
//   n <  1024 : W[h, T-1, k, d]      (h = n>>7, d = n&127)
//   1024..1071: wa columns, c = n-1024 = s*24 + t*8 + h;  sum_d W[h,t,k,d]*a_s[h,t,d]
//   1072..1151: 0
// ---------------------------------------------------------------------------
__global__ void pack_kernel(const float* __restrict__ W, const float* __restrict__ a1,
                            const float* __restrict__ a2, float* __restrict__ Bp) {
    int k = blockIdx.x;  // 0..1023
    for (int n = threadIdx.x; n < NCOLS; n += blockDim.x) {
        float v;
        if (n < 1024) {
            int h = n >> 7, d = n & 127;
            v = W[((size_t)((h * 3 + 2) * 1024) + k) * 128 + d];
        } else if (n < 1072) {
            int c = n - 1024;
            int s = c / 24, rem = c % 24, t = rem >> 3, h = rem & 7;
            const float* a = s ? a2 : a1;
            const float* wrow = W + ((size_t)((h * 3 + t) * 1024) + k) * 128;
            const float* arow = a + (h * 3 + t) * 128;
            float acc = 0.f;
            #pragma unroll 4
            for (int dd = 0; dd < 128; ++dd) acc += wrow[dd] * arow[dd];
            v = acc;
        } else {
            v = 0.f;
        }
        Bp[(size_t)k * NCOLS + n] = v;
    }
}

// ---------------------------------------------------------------------------
// Kernel 2: fp32 GEMM  Y[8192][1152] = X[8192][1024] @ Bp[1024][1152]
//   BM=128, BN=128, BK=16, 256 threads, 8x8 per-thread tile (split 4+4).
//   cols < 1024 multiplied by node_mask[m].
// ---------------------------------------------------------------------------
__global__ __launch_bounds__(256) void gemm_kernel(const float* __restrict__ X,
                                                   const float* __restrict__ Bp,
                                                   const float* __restrict__ nm,
                                                   float* __restrict__ Y) {
    __shared__ float Al[16 * 132];  // A transposed [k][m], padded stride 132
    __shared__ float Bl[16 * 128];  // B [k][n]

    const int n0 = blockIdx.x * 128;  // 0..8  -> n tile
    const int m0 = blockIdx.y * 128;  // 0..63 -> m tile
    const int tid = threadIdx.x;
    const int tx = tid & 15, ty = tid >> 4;

    float acc[8][8];
    #pragma unroll
    for (int r = 0; r < 8; ++r)
        #pragma unroll
        for (int c = 0; c < 8; ++c) acc[r][c] = 0.f;

    for (int k0 = 0; k0 < 1024; k0 += 16) {
        float4 ar[2], br[2];
        #pragma unroll
        for (int q = 0; q < 2; ++q) {
            int idx = tid + 256 * q;
            int m = idx >> 2, k4 = idx & 3;
            ar[q] = *(const float4*)(X + (size_t)(m0 + m) * 1024 + k0 + k4 * 4);
            int kb = idx >> 5, n4 = idx & 31;
            br[q] = *(const float4*)(Bp + (size_t)(k0 + kb) * NCOLS + n0 + n4 * 4);
        }
        __syncthreads();
        #pragma unroll
        for (int q = 0; q < 2; ++q) {
            int idx = tid + 256 * q;
            int m = idx >> 2, k4 = idx & 3;
            Al[(k4 * 4 + 0) * 132 + m] = ar[q].x;
            Al[(k4 * 4 + 1) * 132 + m] = ar[q].y;
            Al[(k4 * 4 + 2) * 132 + m] = ar[q].z;
            Al[(k4 * 4 + 3) * 132 + m] = ar[q].w;
            int kb = idx >> 5, n4 = idx & 31;
            *(float4*)(Bl + kb * 128 + n4 * 4) = br[q];
        }
        __syncthreads();
        #pragma unroll
        for (int kk = 0; kk < 16; ++kk) {
            float4 A0 = *(float4*)(Al + kk * 132 + ty * 4);
            float4 A1 = *(float4*)(Al + kk * 132 + 64 + ty * 4);
            float4 B0 = *(float4*)(Bl + kk * 128 + tx * 4);
            float4 B1 = *(float4*)(Bl + kk * 128 + 64 + tx * 4);
            float av[8] = {A0.x, A0.y, A0.z, A0.w, A1.x, A1.y, A1.z, A1.w};
            float bv[8] = {B0.x, B0.y, B0.z, B0.w, B1.x, B1.y, B1.z, B1.w};
            #pragma unroll
            for (int r = 0; r < 8; ++r)
                #pragma unroll
                for (int c = 0; c < 8; ++c) acc[r][c] += av[r] * bv[c];
        }
    }

    #pragma unroll
    for (int r = 0; r < 8; ++r) {
        int m = m0 + ((r < 4) ? (ty * 4 + r) : (64 + ty * 4 + (r - 4)));
        float mk = nm[m];
        #pragma unroll
        for (int cb = 0; cb < 2; ++cb) {
            int n = n0 + cb * 64 + tx * 4;
            float4 v;
            v.x = acc[r][cb * 4 + 0];
            v.y = acc[r][cb * 4 + 1];
            v.z = acc[r][cb * 4 + 2];
            v.w = acc[r][cb * 4 + 3];
            if (n < 1024) { v.x *= mk; v.y *= mk; v.z *= mk; v.w *= mk; }
            *(float4*)(Y + (size_t)m * NCOLS + n) = v;
        }
    }
}

// ---------------------------------------------------------------------------
// Kernel 3: transpose lr columns of Y into LRt[c][be]  (c = s*24 + t*8 + h)
// ---------------------------------------------------------------------------
__global__ void lrt_kernel(const float* __restrict__ Y, float* __restrict__ LRt) {
    int idx = blockIdx.x * 256 + threadIdx.x;  // 48*8192
    int be = idx & 8191, c = idx >> 13;
    LRt[(size_t)c * 8192 + be] = Y[(size_t)be * NCOLS + 1024 + c];
}

// ---------------------------------------------------------------------------
// Kernel 4: fused scores -> softmax -> aggregation
//   block: 256 threads, one (h, b, 16-row i-tile). grid = 8*16*32 = 4096
// ---------------------------------------------------------------------------
__global__ __launch_bounds__(256) void attn_kernel(const float* __restrict__ Y,
                                                   const float* __restrict__ LRt,
                                                   const int* __restrict__ adj,
                                                   float* __restrict__ out) {
    __shared__ float sc[16 * 520];  // scores -> exp(scores) ; padded stride 520
    __shared__ float rt[3 * 512];   // right[t][j]
    __shared__ float lf[16 * 3];    // left[i][t]
    __shared__ float rs[16];        // 1/rowsum

    const int bid = blockIdx.x;
    const int it = bid & 31, b = (bid >> 5) & 15, h = bid >> 9;
    const int i0 = it * 16;
    const int tid = threadIdx.x;

    for (int idx = tid; idx < 3 * 512; idx += 256) {
        int t = idx >> 9, j = idx & 511;
        rt[idx] = LRt[(size_t)(24 + t * 8 + h) * 8192 + b * 512 + j];
    }
    if (tid < 48) {
        int i = tid / 3, t = tid % 3;
        lf[tid] = LRt[(size_t)(t * 8 + h) * 8192 + b * 512 + i0 + i];
    }
    __syncthreads();

    // scores (adj select + LeakyReLU)
    const int* adjrow = adj + ((size_t)b * 512 + i0) * 512;
    for (int idx = tid; idx < 16 * 512; idx += 256) {
        int i = idx >> 9, j = idx & 511;
        int av = adjrow[i * 512 + j];
        float s;
        if (av == 0) {
            s = NEGV;
        } else {
            float v = lf[i * 3 + (av - 1)] + rt[(av - 1) * 512 + j];
            s = v > 0.f ? v : 0.2f * v;
        }
        sc[i * 520 + j] = s;
    }
    __syncthreads();

    // softmax: 16 threads per row, exp stored back, rowsum inverse kept
    {
        int r = tid >> 4, l = tid & 15;
        float mx = -INFINITY;
        #pragma unroll 8
        for (int m = 0; m < 32; ++m) mx = fmaxf(mx, sc[r * 520 + l + 16 * m]);
        #pragma unroll
        for (int o = 1; o < 16; o <<= 1) mx = fmaxf(mx, __shfl_xor(mx, o));
        float sum = 0.f;
        #pragma unroll 8
        for (int m = 0; m < 32; ++m) {
            float v = __expf(sc[r * 520 + l + 16 * m] - mx);
            sc[r * 520 + l + 16 * m] = v;
            sum += v;
        }
        #pragma unroll
        for (int o = 1; o < 16; o <<= 1) sum += __shfl_xor(sum, o);
        if (l == 0) rs[r] = 1.0f / sum;
    }
    __syncthreads();

    // aggregation: out[i, h*128+d] = relu( (1/sum) * sum_j p[i][j] * hlast[j][d] )
    const int d = tid & 127, iy = tid >> 7;
    float acc[8] = {0, 0, 0, 0, 0, 0, 0, 0};
    const float* Yb = Y + (size_t)(b * 512) * NCOLS + h * 128 + d;
    for (int j4 = 0; j4 < 128; ++j4) {
        float hl[4];
        #pragma unroll
        for (int q = 0; q < 4; ++q) hl[q] = Yb[(size_t)(j4 * 4 + q) * NCOLS];
        #pragma unroll
        for (int r = 0; r < 8; ++r) {
            float4 p = *(float4*)(sc + (iy * 8 + r) * 520 + j4 * 4);
            acc[r] += p.x * hl[0] + p.y * hl[1] + p.z * hl[2] + p.w * hl[3];
        }
    }
    #pragma unroll
    for (int r = 0; r < 8; ++r) {
        int i = iy * 8 + r;
        float v = acc[r] * rs[i];
        out[((size_t)(b * 512 + i0 + i)) * 1024 + h * 128 + d] = fmaxf(v, 0.f);
    }
}

// ---------------------------------------------------------------------------
extern "C" void kernel_launch(void* const* d_in, const int* in_sizes, int n_in,
                              void* d_out, int out_size, void* d_ws, size_t ws_size,
                              hipStream_t stream) {
    const float* x   = (const float*)d_in[0];
    const int*   adj = (const int*)d_in[1];
    const float* nm  = (const float*)d_in[2];
    const float* W   = (const float*)d_in[3];
    const float* a1  = (const float*)d_in[4];
    const float* a2  = (const float*)d_in[5];
    float* out = (float*)d_out;
    float* ws  = (float*)d_ws;

    float* Bp  = ws;
    float* Y   = ws + Y_OFF;
    float* LRt = ws + LR_OFF;

    hipLaunchKernelGGL(pack_kernel, dim3(1024), dim3(256), 0, stream, W, a1, a2, Bp);
    hipLaunchKernelGGL(gemm_kernel, dim3(9, 64), dim3(256), 0, stream, x, Bp, nm, Y);
    hipLaunchKernelGGL(lrt_kernel, dim3(48 * 8192 / 256), dim3(256), 0, stream, Y, LRt);
    hipLaunchKernelGGL(attn_kernel, dim3(8 * 16 * 32), dim3(256), 0, stream, Y, LRt, adj, out);
}

// Round 4
// 353.550 us; speedup vs baseline: 1.5801x; 1.5801x over previous
//
#include <hip/hip_runtime.h>

typedef __attribute__((ext_vector_type(8))) __bf16 bf16x8;
typedef __attribute__((ext_vector_type(8))) unsigned short u16x8;
typedef __attribute__((ext_vector_type(4))) float f32x4;

#define NEGV (-1e30f)

// ---------------------------------------------------------------------------
// Workspace layout (bytes):
//  Bh : [1152][1024] bf16  @ 0          (2,359,296)
//  Bl : [1152][1024] bf16  @ 2359296    (2,359,296)
//  Yh : [8192][1024] bf16  @ 4718592    (16,777,216)  h_last * node_mask
//  LR : [48][8192]  f32    @ 21495808   (1,572,864)   left/right, c = s*24+t*8+h
//  total 23,068,672 B  (fits known-good 44 MB)
// ---------------------------------------------------------------------------

__device__ __forceinline__ unsigned short f2bf(float f) {
    unsigned int u = __float_as_uint(f);
    u += 0x7fffu + ((u >> 16) & 1u);
    return (unsigned short)(u >> 16);
}
__device__ __forceinline__ float b2f(unsigned short h) {
    return __uint_as_float(((unsigned int)h) << 16);
}

// ---------------------------------------------------------------------------
// Kernel 1: pack Bpt[n][k] (transposed, hi/lo bf16 split)
//   n <  1024 : W[h, 2, k, d]   (h=n>>7, d=n&127)
//   1024..1071: c=n-1024 = s*24+t*8+h : sum_d W[h,t,k,d]*a_s[h,t,d]
//   1072..1151: 0
// ---------------------------------------------------------------------------
__global__ __launch_bounds__(256) void pack_kernel(const float* __restrict__ W,
                                                   const float* __restrict__ a1,
                                                   const float* __restrict__ a2,
                                                   unsigned short* __restrict__ Bh,
                                                   unsigned short* __restrict__ Bl) {
    const int n = blockIdx.x;
    const int tid = threadIdx.x;
    if (n < 1024) {
        const int h = n >> 7, d = n & 127;
        const float* w = W + (size_t)(h * 3 + 2) * 1024 * 128 + d;
        for (int k = tid; k < 1024; k += 256) {
            float v = w[(size_t)k * 128];
            unsigned short hi = f2bf(v);
            Bh[(size_t)n * 1024 + k] = hi;
            Bl[(size_t)n * 1024 + k] = f2bf(v - b2f(hi));
        }
    } else if (n < 1072) {
        const int c = n - 1024;
        const int s = c / 24, rem = c % 24, t = rem >> 3, h = rem & 7;
        const float* a = (s ? a2 : a1) + (h * 3 + t) * 128;
        const float* wb = W + (size_t)(h * 3 + t) * 1024 * 128;
        for (int k = tid; k < 1024; k += 256) {
            const float4* wr4 = (const float4*)(wb + (size_t)k * 128);
            const float4* a4 = (const float4*)a;
            float acc = 0.f;
            #pragma unroll 8
            for (int dd = 0; dd < 32; ++dd) {
                float4 wv = wr4[dd], av = a4[dd];
                acc += wv.x * av.x + wv.y * av.y + wv.z * av.z + wv.w * av.w;
            }
            unsigned short hi = f2bf(acc);
            Bh[(size_t)n * 1024 + k] = hi;
            Bl[(size_t)n * 1024 + k] = f2bf(acc - b2f(hi));
        }
    } else {
        for (int k = tid; k < 1024; k += 256) {
            Bh[(size_t)n * 1024 + k] = 0;
            Bl[(size_t)n * 1024 + k] = 0;
        }
    }
}

// ---------------------------------------------------------------------------
// Kernel 2: bf16x3 MFMA GEMM  [8192 x 1152] = X[8192][1024] (split) @ Bpt^T
//   128x128 tile, BK=32, 4 waves (2x2), mfma_f32_16x16x32_bf16.
//   A reg-staged (f32 -> hi/lo bf16 -> ds_write), B via global_load_lds w=16.
//   Epilogue: cols<1024 -> Yh bf16 (*node_mask); cols 1024..1071 -> LR f32.
// ---------------------------------------------------------------------------
__global__ __launch_bounds__(256, 3) void mgemm(const float* __restrict__ X,
                                                const unsigned short* __restrict__ Bh,
                                                const unsigned short* __restrict__ Bl,
                                                const float* __restrict__ nm,
                                                unsigned short* __restrict__ Yh,
                                                float* __restrict__ LR) {
    __shared__ unsigned short Ah[128 * 32];
    __shared__ unsigned short Al[128 * 32];
    __shared__ unsigned short Bhs[128 * 32];
    __shared__ unsigned short Bls[128 * 32];

    const int bid = blockIdx.x;                 // 0..575
    const int swz = (bid & 7) * 72 + (bid >> 3); // XCD-aware, bijective (576 = 8*72)
    const int nt = swz % 9, mt = swz / 9;
    const int n0 = nt * 128, m0 = mt * 128;

    const int tid = threadIdx.x;
    const int lane = tid & 63, w = tid >> 6;
    const int wr = w >> 1, wc = w & 1;
    const int fr = lane & 15, fq = lane >> 4;

    f32x4 acc[4][4];
    #pragma unroll
    for (int m = 0; m < 4; ++m)
        #pragma unroll
        for (int n = 0; n < 4; ++n) acc[m][n] = (f32x4){0.f, 0.f, 0.f, 0.f};

    // A staging role: row = tid>>1 (0..127), half = tid&1 (16 floats each)
    const int arow = tid >> 1, ahalf = tid & 1;
    const float* xs = X + (size_t)(m0 + arow) * 1024 + ahalf * 16;
    unsigned short* adh = Ah + arow * 32 + ahalf * 16;
    unsigned short* adl = Al + arow * 32 + ahalf * 16;

    for (int k0 = 0; k0 < 1024; k0 += 32) {
        __syncthreads();  // previous compute done before LDS overwrite

        // ---- B tiles: global_load_lds, 16B per lane, linear layout [row][32k]
        #pragma unroll
        for (int q = 0; q < 2; ++q) {
            const int s = q * 256 + tid;
            const int brow = s >> 2, bkb = s & 3;
            const unsigned short* gh = Bh + (size_t)(n0 + brow) * 1024 + k0 + bkb * 8;
            const unsigned short* gl = Bl + (size_t)(n0 + brow) * 1024 + k0 + bkb * 8;
            unsigned short* dh = Bhs + (q * 256 + w * 64) * 8;
            unsigned short* dl = Bls + (q * 256 + w * 64) * 8;
            __builtin_amdgcn_global_load_lds(
                (const __attribute__((address_space(1))) void*)gh,
                (__attribute__((address_space(3))) void*)dh, 16, 0, 0);
            __builtin_amdgcn_global_load_lds(
                (const __attribute__((address_space(1))) void*)gl,
                (__attribute__((address_space(3))) void*)dl, 16, 0, 0);
        }

        // ---- A tile: f32 load -> hi/lo split -> ds_write_b128
        float xf[16];
        #pragma unroll
        for (int i = 0; i < 4; ++i) {
            float4 v = *(const float4*)(xs + k0 + i * 4);
            xf[i * 4 + 0] = v.x; xf[i * 4 + 1] = v.y;
            xf[i * 4 + 2] = v.z; xf[i * 4 + 3] = v.w;
        }
        u16x8 vh0, vh1, vl0, vl1;
        #pragma unroll
        for (int i = 0; i < 8; ++i) {
            unsigned short hi = f2bf(xf[i]);
            vh0[i] = hi;
            vl0[i] = f2bf(xf[i] - b2f(hi));
        }
        #pragma unroll
        for (int i = 0; i < 8; ++i) {
            unsigned short hi = f2bf(xf[8 + i]);
            vh1[i] = hi;
            vl1[i] = f2bf(xf[8 + i] - b2f(hi));
        }
        *(u16x8*)(adh) = vh0;
        *(u16x8*)(adh + 8) = vh1;
        *(u16x8*)(adl) = vl0;
        *(u16x8*)(adl + 8) = vl1;

        __syncthreads();  // vmcnt(0)+lgkmcnt(0) drain by compiler

        // ---- fragments + 48 MFMAs (3 phases, cap live frags at 12)
        bf16x8 amh[4], bnh[4];
        #pragma unroll
        for (int m = 0; m < 4; ++m)
            amh[m] = *(bf16x8*)(Ah + (wr * 64 + m * 16 + fr) * 32 + fq * 8);
        #pragma unroll
        for (int n = 0; n < 4; ++n)
            bnh[n] = *(bf16x8*)(Bhs + (wc * 64 + n * 16 + fr) * 32 + fq * 8);
        #pragma unroll
        for (int m = 0; m < 4; ++m)
            #pragma unroll
            for (int n = 0; n < 4; ++n)
                acc[m][n] = __builtin_amdgcn_mfma_f32_16x16x32_bf16(amh[m], bnh[n], acc[m][n], 0, 0, 0);

        bf16x8 bnl[4];
        #pragma unroll
        for (int n = 0; n < 4; ++n)
            bnl[n] = *(bf16x8*)(Bls + (wc * 64 + n * 16 + fr) * 32 + fq * 8);
        #pragma unroll
        for (int m = 0; m < 4; ++m)
            #pragma unroll
            for (int n = 0; n < 4; ++n)
                acc[m][n] = __builtin_amdgcn_mfma_f32_16x16x32_bf16(amh[m], bnl[n], acc[m][n], 0, 0, 0);

        bf16x8 aml[4];
        #pragma unroll
        for (int m = 0; m < 4; ++m)
            aml[m] = *(bf16x8*)(Al + (wr * 64 + m * 16 + fr) * 32 + fq * 8);
        #pragma unroll
        for (int m = 0; m < 4; ++m)
            #pragma unroll
            for (int n = 0; n < 4; ++n)
                acc[m][n] = __builtin_amdgcn_mfma_f32_16x16x32_bf16(aml[m], bnh[n], acc[m][n], 0, 0, 0);
    }

    // ---- epilogue: C/D layout col=lane&15, row=(lane>>4)*4+reg
    #pragma unroll
    for (int m = 0; m < 4; ++m) {
        #pragma unroll
        for (int r = 0; r < 4; ++r) {
            const int R = m0 + wr * 64 + m * 16 + fq * 4 + r;
            const float mk = nm[R];
            #pragma unroll
            for (int n = 0; n < 4; ++n) {
                const int col = n0 + wc * 64 + n * 16 + fr;
                const float v = acc[m][n][r];
                if (col < 1024) {
                    Yh[(size_t)R * 1024 + col] = f2bf(v * mk);
                } else {
                    const int c = col - 1024;
                    if (c < 48) LR[(size_t)c * 8192 + R] = v;
                }
            }
        }
    }
}

// ---------------------------------------------------------------------------
// Kernel 3: fused scores -> softmax -> aggregation (unchanged structure;
//           h_last read as bf16, left/right read from LR directly)
// ---------------------------------------------------------------------------
__global__ __launch_bounds__(256) void attn_kernel(const unsigned short* __restrict__ Yh,
                                                   const float* __restrict__ LR,
                                                   const int* __restrict__ adj,
                                                   float* __restrict__ out) {
    __shared__ float sc[16 * 520];
    __shared__ float rt[3 * 512];
    __shared__ float lf[16 * 3];
    __shared__ float rs[16];

    const int bid = blockIdx.x;
    const int it = bid & 31, b = (bid >> 5) & 15, h = bid >> 9;
    const int i0 = it * 16;
    const int tid = threadIdx.x;

    for (int idx = tid; idx < 3 * 512; idx += 256) {
        int t = idx >> 9, j = idx & 511;
        rt[idx] = LR[(size_t)(24 + t * 8 + h) * 8192 + b * 512 + j];
    }
    if (tid < 48) {
        int i = tid / 3, t = tid % 3;
        lf[tid] = LR[(size_t)(t * 8 + h) * 8192 + b * 512 + i0 + i];
    }
    __syncthreads();

    const int* adjrow = adj + ((size_t)b * 512 + i0) * 512;
    for (int idx = tid; idx < 16 * 512; idx += 256) {
        int i = idx >> 9, j = idx & 511;
        int av = adjrow[i * 512 + j];
        float s;
        if (av == 0) {
            s = NEGV;
        } else {
            float v = lf[i * 3 + (av - 1)] + rt[(av - 1) * 512 + j];
            s = v > 0.f ? v : 0.2f * v;
        }
        sc[i * 520 + j] = s;
    }
    __syncthreads();

    {
        int r = tid >> 4, l = tid & 15;
        float mx = -INFINITY;
        #pragma unroll 8
        for (int m = 0; m < 32; ++m) mx = fmaxf(mx, sc[r * 520 + l + 16 * m]);
        #pragma unroll
        for (int o = 1; o < 16; o <<= 1) mx = fmaxf(mx, __shfl_xor(mx, o));
        float sum = 0.f;
        #pragma unroll 8
        for (int m = 0; m < 32; ++m) {
            float v = __expf(sc[r * 520 + l + 16 * m] - mx);
            sc[r * 520 + l + 16 * m] = v;
            sum += v;
        }
        #pragma unroll
        for (int o = 1; o < 16; o <<= 1) sum += __shfl_xor(sum, o);
        if (l == 0) rs[r] = 1.0f / sum;
    }
    __syncthreads();

    const int d = tid & 127, iy = tid >> 7;
    float acc[8] = {0, 0, 0, 0, 0, 0, 0, 0};
    const unsigned short* Yb = Yh + (size_t)(b * 512) * 1024 + h * 128 + d;
    for (int j4 = 0; j4 < 128; ++j4) {
        float hl[4];
        #pragma unroll
        for (int q = 0; q < 4; ++q) hl[q] = b2f(Yb[(size_t)(j4 * 4 + q) * 1024]);
        #pragma unroll
        for (int r = 0; r < 8; ++r) {
            float4 p = *(float4*)(sc + (iy * 8 + r) * 520 + j4 * 4);
            acc[r] += p.x * hl[0] + p.y * hl[1] + p.z * hl[2] + p.w * hl[3];
        }
    }
    #pragma unroll
    for (int r = 0; r < 8; ++r) {
        int i = iy * 8 + r;
        float v = acc[r] * rs[i];
        out[((size_t)(b * 512 + i0 + i)) * 1024 + h * 128 + d] = fmaxf(v, 0.f);
    }
}

// ---------------------------------------------------------------------------
extern "C" void kernel_launch(void* const* d_in, const int* in_sizes, int n_in,
                              void* d_out, int out_size, void* d_ws, size_t ws_size,
                              hipStream_t stream) {
    const float* x   = (const float*)d_in[0];
    const int*   adj = (const int*)d_in[1];
    const float* nm  = (const float*)d_in[2];
    const float* W   = (const float*)d_in[3];
    const float* a1  = (const float*)d_in[4];
    const float* a2  = (const float*)d_in[5];
    float* out = (float*)d_out;
    char* wsb = (char*)d_ws;

    unsigned short* Bh = (unsigned short*)(wsb);
    unsigned short* Bl = (unsigned short*)(wsb + 2359296);
    unsigned short* Yh = (unsigned short*)(wsb + 4718592);
    float*          LR = (float*)(wsb + 21495808);

    hipLaunchKernelGGL(pack_kernel, dim3(1152), dim3(256), 0, stream, W, a1, a2, Bh, Bl);
    hipLaunchKernelGGL(mgemm, dim3(576), dim3(256), 0, stream, x, Bh, Bl, nm, Yh, LR);
    hipLaunchKernelGGL(attn_kernel, dim3(4096), dim3(256), 0, stream, Yh, LR, adj, out);
}

// Round 5
// 204.825 us; speedup vs baseline: 2.7274x; 1.7261x over previous
//
#include <hip/hip_runtime.h>

typedef __attribute__((ext_vector_type(8))) __bf16 bf16x8;
typedef __attribute__((ext_vector_type(8))) unsigned short u16x8;
typedef __attribute__((ext_vector_type(4))) float f32x4;

#define NEGV (-1e30f)

// ---------------------------------------------------------------------------
// Workspace layout (bytes):
//  Bh : [1152][1024] bf16  @ 0          (2,359,296)
//  Bl : [1152][1024] bf16  @ 2359296    (2,359,296)
//  Yh : [8192][1024] bf16  @ 4718592    (16,777,216)  h_last * node_mask
//  LR : [48][8192]  f32    @ 21495808   (1,572,864)   left/right, c = s*24+t*8+h
//  Vt : [8][16][128][512] bf16 @ 23068672 (16,777,216) transposed h_last
//  total 39,845,888 B (fits known-good 44 MB)
// ---------------------------------------------------------------------------

__device__ __forceinline__ unsigned short f2bf(float f) {
    unsigned int u = __float_as_uint(f);
    u += 0x7fffu + ((u >> 16) & 1u);
    return (unsigned short)(u >> 16);
}
__device__ __forceinline__ float b2f(unsigned short h) {
    return __uint_as_float(((unsigned int)h) << 16);
}

// ---------------------------------------------------------------------------
// Kernel 1: pack Bpt[n][k] (transposed, hi/lo bf16 split)  [unchanged]
// ---------------------------------------------------------------------------
__global__ __launch_bounds__(256) void pack_kernel(const float* __restrict__ W,
                                                   const float* __restrict__ a1,
                                                   const float* __restrict__ a2,
                                                   unsigned short* __restrict__ Bh,
                                                   unsigned short* __restrict__ Bl) {
    const int n = blockIdx.x;
    const int tid = threadIdx.x;
    if (n < 1024) {
        const int h = n >> 7, d = n & 127;
        const float* w = W + (size_t)(h * 3 + 2) * 1024 * 128 + d;
        for (int k = tid; k < 1024; k += 256) {
            float v = w[(size_t)k * 128];
            unsigned short hi = f2bf(v);
            Bh[(size_t)n * 1024 + k] = hi;
            Bl[(size_t)n * 1024 + k] = f2bf(v - b2f(hi));
        }
    } else if (n < 1072) {
        const int c = n - 1024;
        const int s = c / 24, rem = c % 24, t = rem >> 3, h = rem & 7;
        const float* a = (s ? a2 : a1) + (h * 3 + t) * 128;
        const float* wb = W + (size_t)(h * 3 + t) * 1024 * 128;
        for (int k = tid; k < 1024; k += 256) {
            const float4* wr4 = (const float4*)(wb + (size_t)k * 128);
            const float4* a4 = (const float4*)a;
            float acc = 0.f;
            #pragma unroll 8
            for (int dd = 0; dd < 32; ++dd) {
                float4 wv = wr4[dd], av = a4[dd];
                acc += wv.x * av.x + wv.y * av.y + wv.z * av.z + wv.w * av.w;
            }
            unsigned short hi = f2bf(acc);
            Bh[(size_t)n * 1024 + k] = hi;
            Bl[(size_t)n * 1024 + k] = f2bf(acc - b2f(hi));
        }
    } else {
        for (int k = tid; k < 1024; k += 256) {
            Bh[(size_t)n * 1024 + k] = 0;
            Bl[(size_t)n * 1024 + k] = 0;
        }
    }
}

// ---------------------------------------------------------------------------
// Kernel 2: bf16x3 MFMA GEMM  [unchanged from round 4 — verified 353us total]
// ---------------------------------------------------------------------------
__global__ __launch_bounds__(256, 3) void mgemm(const float* __restrict__ X,
                                                const unsigned short* __restrict__ Bh,
                                                const unsigned short* __restrict__ Bl,
                                                const float* __restrict__ nm,
                                                unsigned short* __restrict__ Yh,
                                                float* __restrict__ LR) {
    __shared__ unsigned short Ah[128 * 32];
    __shared__ unsigned short Al[128 * 32];
    __shared__ unsigned short Bhs[128 * 32];
    __shared__ unsigned short Bls[128 * 32];

    const int bid = blockIdx.x;
    const int swz = (bid & 7) * 72 + (bid >> 3);
    const int nt = swz % 9, mt = swz / 9;
    const int n0 = nt * 128, m0 = mt * 128;

    const int tid = threadIdx.x;
    const int lane = tid & 63, w = tid >> 6;
    const int wr = w >> 1, wc = w & 1;
    const int fr = lane & 15, fq = lane >> 4;

    f32x4 acc[4][4];
    #pragma unroll
    for (int m = 0; m < 4; ++m)
        #pragma unroll
        for (int n = 0; n < 4; ++n) acc[m][n] = (f32x4){0.f, 0.f, 0.f, 0.f};

    const int arow = tid >> 1, ahalf = tid & 1;
    const float* xs = X + (size_t)(m0 + arow) * 1024 + ahalf * 16;
    unsigned short* adh = Ah + arow * 32 + ahalf * 16;
    unsigned short* adl = Al + arow * 32 + ahalf * 16;

    for (int k0 = 0; k0 < 1024; k0 += 32) {
        __syncthreads();

        #pragma unroll
        for (int q = 0; q < 2; ++q) {
            const int s = q * 256 + tid;
            const int brow = s >> 2, bkb = s & 3;
            const unsigned short* gh = Bh + (size_t)(n0 + brow) * 1024 + k0 + bkb * 8;
            const unsigned short* gl = Bl + (size_t)(n0 + brow) * 1024 + k0 + bkb * 8;
            unsigned short* dh = Bhs + (q * 256 + w * 64) * 8;
            unsigned short* dl = Bls + (q * 256 + w * 64) * 8;
            __builtin_amdgcn_global_load_lds(
                (const __attribute__((address_space(1))) void*)gh,
                (__attribute__((address_space(3))) void*)dh, 16, 0, 0);
            __builtin_amdgcn_global_load_lds(
                (const __attribute__((address_space(1))) void*)gl,
                (__attribute__((address_space(3))) void*)dl, 16, 0, 0);
        }

        float xf[16];
        #pragma unroll
        for (int i = 0; i < 4; ++i) {
            float4 v = *(const float4*)(xs + k0 + i * 4);
            xf[i * 4 + 0] = v.x; xf[i * 4 + 1] = v.y;
            xf[i * 4 + 2] = v.z; xf[i * 4 + 3] = v.w;
        }
        u16x8 vh0, vh1, vl0, vl1;
        #pragma unroll
        for (int i = 0; i < 8; ++i) {
            unsigned short hi = f2bf(xf[i]);
            vh0[i] = hi;
            vl0[i] = f2bf(xf[i] - b2f(hi));
        }
        #pragma unroll
        for (int i = 0; i < 8; ++i) {
            unsigned short hi = f2bf(xf[8 + i]);
            vh1[i] = hi;
            vl1[i] = f2bf(xf[8 + i] - b2f(hi));
        }
        *(u16x8*)(adh) = vh0;
        *(u16x8*)(adh + 8) = vh1;
        *(u16x8*)(adl) = vl0;
        *(u16x8*)(adl + 8) = vl1;

        __syncthreads();

        bf16x8 amh[4], bnh[4];
        #pragma unroll
        for (int m = 0; m < 4; ++m)
            amh[m] = *(bf16x8*)(Ah + (wr * 64 + m * 16 + fr) * 32 + fq * 8);
        #pragma unroll
        for (int n = 0; n < 4; ++n)
            bnh[n] = *(bf16x8*)(Bhs + (wc * 64 + n * 16 + fr) * 32 + fq * 8);
        #pragma unroll
        for (int m = 0; m < 4; ++m)
            #pragma unroll
            for (int n = 0; n < 4; ++n)
                acc[m][n] = __builtin_amdgcn_mfma_f32_16x16x32_bf16(amh[m], bnh[n], acc[m][n], 0, 0, 0);

        bf16x8 bnl[4];
        #pragma unroll
        for (int n = 0; n < 4; ++n)
            bnl[n] = *(bf16x8*)(Bls + (wc * 64 + n * 16 + fr) * 32 + fq * 8);
        #pragma unroll
        for (int m = 0; m < 4; ++m)
            #pragma unroll
            for (int n = 0; n < 4; ++n)
                acc[m][n] = __builtin_amdgcn_mfma_f32_16x16x32_bf16(amh[m], bnl[n], acc[m][n], 0, 0, 0);

        bf16x8 aml[4];
        #pragma unroll
        for (int m = 0; m < 4; ++m)
            aml[m] = *(bf16x8*)(Al + (wr * 64 + m * 16 + fr) * 32 + fq * 8);
        #pragma unroll
        for (int m = 0; m < 4; ++m)
            #pragma unroll
            for (int n = 0; n < 4; ++n)
                acc[m][n] = __builtin_amdgcn_mfma_f32_16x16x32_bf16(aml[m], bnh[n], acc[m][n], 0, 0, 0);
    }

    #pragma unroll
    for (int m = 0; m < 4; ++m) {
        #pragma unroll
        for (int r = 0; r < 4; ++r) {
            const int R = m0 + wr * 64 + m * 16 + fq * 4 + r;
            const float mk = nm[R];
            #pragma unroll
            for (int n = 0; n < 4; ++n) {
                const int col = n0 + wc * 64 + n * 16 + fr;
                const float v = acc[m][n][r];
                if (col < 1024) {
                    Yh[(size_t)R * 1024 + col] = f2bf(v * mk);
                } else {
                    const int c = col - 1024;
                    if (c < 48) LR[(size_t)c * 8192 + R] = v;
                }
            }
        }
    }
}

// ---------------------------------------------------------------------------
// Kernel 3: transpose Yh[b*512+j][h*128+d] -> Vt[h][b][d][j]
//   block = (h, b, 64-row j-tile); 64j x 128d tile through LDS
// ---------------------------------------------------------------------------
__global__ __launch_bounds__(256) void vt_kernel(const unsigned short* __restrict__ Yh,
                                                 unsigned short* __restrict__ Vt) {
    __shared__ __align__(16) unsigned short tile[64 * 136];
    const int bid = blockIdx.x;              // 1024 = 8h * 16b * 8jt
    const int jt = bid & 7, b = (bid >> 3) & 15, h = bid >> 7;
    const int j0 = jt * 64;
    const int tid = threadIdx.x;

    #pragma unroll
    for (int rep = 0; rep < 4; ++rep) {
        int idx = rep * 256 + tid;           // 1024 chunks of 8 ushort
        int j = idx >> 4, dc = (idx & 15) * 8;
        u16x8 v = *(const u16x8*)(Yh + (size_t)(b * 512 + j0 + j) * 1024 + h * 128 + dc);
        *(u16x8*)(tile + j * 136 + dc) = v;
    }
    __syncthreads();
    #pragma unroll
    for (int rep = 0; rep < 4; ++rep) {
        int idx = rep * 256 + tid;
        int d = idx >> 3, jc = (idx & 7) * 8;
        u16x8 o;
        #pragma unroll
        for (int q = 0; q < 8; ++q) o[q] = tile[(jc + q) * 136 + d];
        *(u16x8*)(Vt + ((size_t)(h * 16 + b) * 128 + d) * 512 + j0 + jc) = o;
    }
}

// ---------------------------------------------------------------------------
// Kernel 4: fused scores -> softmax -> MFMA aggregation
//   block = (b, 16-row i-tile), 256 thr (4 waves), all 8 h in-block.
//   P kept as bf16 hi/lo in LDS; PV = mfma_16x16x32_bf16, V from Vt (L2).
// ---------------------------------------------------------------------------
__global__ __launch_bounds__(256) void attn_kernel(const unsigned short* __restrict__ Vt,
                                                   const float* __restrict__ LR,
                                                   const int* __restrict__ adj,
                                                   float* __restrict__ out) {
    __shared__ __align__(16) unsigned short Ph[16 * 520];
    __shared__ __align__(16) unsigned short Pl[16 * 520];
    __shared__ float rt[3 * 512];
    __shared__ unsigned char adjb[16 * 512];
    __shared__ float rs[16];

    const int bid = blockIdx.x;              // 512 = 16 b * 32 itile
    const int it = bid & 31, b = bid >> 5;
    const int i0 = it * 16;
    const int tid = threadIdx.x;
    const int lane = tid & 63, w = tid >> 6;
    const int fr = lane & 15, fq = lane >> 4;
    const int r = tid >> 4, l = tid & 15;    // score-phase: 16 rows x 16 lanes

    // stage adj tile as bytes (once)
    const int* adjt = adj + ((size_t)(b * 512 + i0)) * 512;
    #pragma unroll
    for (int rep = 0; rep < 8; ++rep) {
        int idx4 = rep * 256 + tid;          // 2048 dwords of packed bytes
        int4 v = *(const int4*)(adjt + idx4 * 4);
        uchar4 pk;
        pk.x = (unsigned char)v.x; pk.y = (unsigned char)v.y;
        pk.z = (unsigned char)v.z; pk.w = (unsigned char)v.w;
        *(uchar4*)(adjb + idx4 * 4) = pk;
    }

    for (int h = 0; h < 8; ++h) {
        // ---- stage rt (3x512 f32) + lf in regs
        for (int idx = tid; idx < 1536; idx += 256) {
            int t = idx >> 9, j = idx & 511;
            rt[idx] = LR[(size_t)(24 + t * 8 + h) * 8192 + b * 512 + j];
        }
        float lf0 = LR[(size_t)(0 * 8 + h) * 8192 + b * 512 + i0 + r];
        float lf1 = LR[(size_t)(1 * 8 + h) * 8192 + b * 512 + i0 + r];
        float lf2 = LR[(size_t)(2 * 8 + h) * 8192 + b * 512 + i0 + r];
        __syncthreads();   // rt ready; also: all waves done with prev h's Ph/rs

        // ---- scores in registers (fully unrolled -> no scratch)
        float s[32];
        #pragma unroll
        for (int m = 0; m < 32; ++m) {
            int j = l + 16 * m;
            int av = adjb[r * 512 + j];
            int t = (av > 0) ? (av - 1) : 0;
            float base = (t == 0 ? lf0 : (t == 1 ? lf1 : lf2)) + rt[t * 512 + j];
            float v = base > 0.f ? base : 0.2f * base;
            s[m] = (av > 0) ? v : NEGV;
        }
        float mx = s[0];
        #pragma unroll
        for (int m = 1; m < 32; ++m) mx = fmaxf(mx, s[m]);
        #pragma unroll
        for (int o = 1; o < 16; o <<= 1) mx = fmaxf(mx, __shfl_xor(mx, o));
        float sum = 0.f;
        #pragma unroll
        for (int m = 0; m < 32; ++m) {
            float p = __expf(s[m] - mx);
            sum += p;
            unsigned short hi = f2bf(p);
            Ph[r * 520 + l + 16 * m] = hi;
            Pl[r * 520 + l + 16 * m] = f2bf(p - b2f(hi));
        }
        #pragma unroll
        for (int o = 1; o < 16; o <<= 1) sum += __shfl_xor(sum, o);
        if (l == 0) rs[r] = 1.0f / sum;
        __syncthreads();   // Ph/Pl/rs ready

        // ---- PV via MFMA: wave w owns d-cols [w*32, w*32+32)
        f32x4 acc0 = (f32x4){0.f, 0.f, 0.f, 0.f};
        f32x4 acc1 = (f32x4){0.f, 0.f, 0.f, 0.f};
        const unsigned short* vt = Vt + ((size_t)(h * 16 + b) * 128 + w * 32) * 512;
        #pragma unroll
        for (int k0 = 0; k0 < 16; ++k0) {
            bf16x8 ah = *(bf16x8*)(Ph + fr * 520 + k0 * 32 + fq * 8);
            bf16x8 al = *(bf16x8*)(Pl + fr * 520 + k0 * 32 + fq * 8);
            bf16x8 b0 = *(const bf16x8*)(vt + (size_t)fr * 512 + k0 * 32 + fq * 8);
            bf16x8 b1 = *(const bf16x8*)(vt + (size_t)(16 + fr) * 512 + k0 * 32 + fq * 8);
            acc0 = __builtin_amdgcn_mfma_f32_16x16x32_bf16(ah, b0, acc0, 0, 0, 0);
            acc0 = __builtin_amdgcn_mfma_f32_16x16x32_bf16(al, b0, acc0, 0, 0, 0);
            acc1 = __builtin_amdgcn_mfma_f32_16x16x32_bf16(ah, b1, acc1, 0, 0, 0);
            acc1 = __builtin_amdgcn_mfma_f32_16x16x32_bf16(al, b1, acc1, 0, 0, 0);
        }

        // ---- epilogue: C/D layout col=lane&15, row=(lane>>4)*4+reg
        #pragma unroll
        for (int rr = 0; rr < 4; ++rr) {
            int row = fq * 4 + rr;
            float scale = rs[row];
            float v0 = fmaxf(acc0[rr] * scale, 0.f);
            float v1 = fmaxf(acc1[rr] * scale, 0.f);
            size_t o = (size_t)(b * 512 + i0 + row) * 1024 + h * 128 + w * 32 + fr;
            out[o] = v0;
            out[o + 16] = v1;
        }
    }
}

// ---------------------------------------------------------------------------
extern "C" void kernel_launch(void* const* d_in, const int* in_sizes, int n_in,
                              void* d_out, int out_size, void* d_ws, size_t ws_size,
                              hipStream_t stream) {
    const float* x   = (const float*)d_in[0];
    const int*   adj = (const int*)d_in[1];
    const float* nm  = (const float*)d_in[2];
    const float* W   = (const float*)d_in[3];
    const float* a1  = (const float*)d_in[4];
    const float* a2  = (const float*)d_in[5];
    float* out = (float*)d_out;
    char* wsb = (char*)d_ws;

    unsigned short* Bh = (unsigned short*)(wsb);
    unsigned short* Bl = (unsigned short*)(wsb + 2359296);
    unsigned short* Yh = (unsigned short*)(wsb + 4718592);
    float*          LR = (float*)(wsb + 21495808);
    unsigned short* Vt = (unsigned short*)(wsb + 23068672);

    hipLaunchKernelGGL(pack_kernel, dim3(1152), dim3(256), 0, stream, W, a1, a2, Bh, Bl);
    hipLaunchKernelGGL(mgemm, dim3(576), dim3(256), 0, stream, x, Bh, Bl, nm, Yh, LR);
    hipLaunchKernelGGL(vt_kernel, dim3(1024), dim3(256), 0, stream, Yh, Vt);
    hipLaunchKernelGGL(attn_kernel, dim3(512), dim3(256), 0, stream, Vt, LR, adj, out);
}